// Round 1
// baseline (9781.936 us; speedup 1.0000x reference)
//
#include <hip/hip_runtime.h>
#include <hip/hip_cooperative_groups.h>
#include <hip/hip_bf16.h>

namespace cg = cooperative_groups;

typedef __bf16 bf16_t;
typedef __bf16 bf16x8 __attribute__((ext_vector_type(8)));
typedef float floatx4 __attribute__((ext_vector_type(4)));

#define LAYERS 8
#define BATCH  64
#define TSEQ   256
#define HDIM   512
#define GDIM   2048   // 4*H
#define KDIM   1024   // concat [x(512); h(512)]
#define UNITS  16     // LSTM units per CU slice
#define NROWS  64     // gate rows per CU slice (16 each of i,f,g,o)
#define WROW   1032   // LDS row stride in bf16 elems (1024 + 8 pad)

// LDS layout (bytes)
#define W_OFF      0
#define W_BYTES    (NROWS * WROW * 2)          // 132096
#define GATES_OFF  (W_OFF + W_BYTES)           // fp32 [64 batch][64 gates]
#define GATES_BYTES (BATCH * NROWS * 4)        // 16384
#define C_OFF      (GATES_OFF + GATES_BYTES)   // fp32 [64 batch][16 units]
#define C_BYTES    (BATCH * UNITS * 4)         // 4096
#define BIAS_OFF   (C_OFF + C_BYTES)           // fp32 [64]
#define BIAS_BYTES (NROWS * 4)                 // 256
#define LDS_TOTAL  (BIAS_OFF + BIAS_BYTES)     // 152832

__device__ __forceinline__ floatx4 mfma16(bf16x8 a, bf16x8 b, floatx4 c) {
    return __builtin_amdgcn_mfma_f32_16x16x32_bf16(a, b, c, 0, 0, 0);
}

__device__ __forceinline__ float sigm(float x) {
    return 1.0f / (1.0f + __expf(-x));
}

// Cooperative kernel: 256 blocks x 512 threads, 1 block/CU.
// block -> (layer = blk & 7, slice = blk >> 3). Layer l's 32 blocks all share
// blk%8 == l, which lands them on one XCD under round-robin dispatch (L2
// locality for the h broadcast). Each block owns 16 LSTM units = 64 gate rows
// (i,f,g,o x16), weights resident in LDS for all 256 timesteps.
__global__ void lstm_main(const float* __restrict__ x,
                          const float* __restrict__ w_ih,
                          const float* __restrict__ w_hh,
                          const float* __restrict__ b_ih,
                          const float* __restrict__ b_hh,
                          bf16_t* __restrict__ x_bf,    // [T][B][H]
                          bf16_t* __restrict__ h_buf,   // [L][2][B][H]
                          float*  __restrict__ finals)  // [B][L][H]
{
    extern __shared__ char smem[];
    bf16_t* wlds  = (bf16_t*)(smem + W_OFF);
    float*  gates = (float*)(smem + GATES_OFF);
    float*  cst   = (float*)(smem + C_OFF);
    float*  bias  = (float*)(smem + BIAS_OFF);

    const int tid   = threadIdx.x;
    const int blk   = blockIdx.x;
    const int layer = blk & 7;
    const int slice = blk >> 3;
    const int u0    = slice * UNITS;

    // ---- prep: x -> bf16 transposed [t][b][e]; zero h ping-pong buffers ----
    {
        const int gtid = blk * blockDim.x + tid;
        const int nthr = gridDim.x * blockDim.x;   // 131072
        for (int i = gtid; i < BATCH * TSEQ * HDIM; i += nthr) {
            int e = i & (HDIM - 1);
            int b = (i >> 9) & 63;
            int t = i >> 15;
            x_bf[i] = (bf16_t)x[((size_t)b * TSEQ + t) * HDIM + e];
        }
        for (int i = gtid; i < LAYERS * 2 * BATCH * HDIM; i += nthr)
            h_buf[i] = (bf16_t)0.0f;
    }

    // ---- load this block's weight slice into LDS (bf16), rows = 64 gates ----
    // row r: gate = (r>>4)*512 + u0 + (r&15)   (i/f/g/o quadruple layout)
    for (int r = 0; r < NROWS; ++r) {
        const int gate = ((r >> 4) * 512) + u0 + (r & 15);
        const float* srcA = w_ih + ((size_t)layer * GDIM + gate) * HDIM;
        const float* srcB = w_hh + ((size_t)layer * GDIM + gate) * HDIM;
        wlds[r * WROW + tid]       = (bf16_t)srcA[tid];   // k in [0,512)
        wlds[r * WROW + 512 + tid] = (bf16_t)srcB[tid];   // k in [512,1024)
    }
    if (tid < NROWS) {
        const int gate = ((tid >> 4) * 512) + u0 + (tid & 15);
        bias[tid] = b_ih[layer * GDIM + gate] + b_hh[layer * GDIM + gate];
    }
    for (int i = tid; i < BATCH * UNITS; i += blockDim.x) cst[i] = 0.0f;

    cg::grid_group grid = cg::this_grid();
    grid.sync();

    // ---- wave/tile assignment: 8 waves, each owns m-tile (batch16) x 2 n-tiles ----
    const int lane = tid & 63;
    const int wave = tid >> 6;
    const int quad = lane >> 4;
    const int l15  = lane & 15;
    const int m0   = (wave & 3) * 16;        // batch tile base
    const int nb0  = (wave >> 2) * 32;       // first of two 16-gate n-tiles

    const int arow = m0 + l15;
    const bf16_t* b_base0 = wlds + (size_t)(nb0 + l15) * WROW + quad * 8;
    const bf16_t* b_base1 = b_base0 + (size_t)16 * WROW;

    // ---- wavefront-pipelined supersteps: layer l computes t = s - l ----
    for (int s = 0; s < TSEQ + LAYERS - 1; ++s) {
        const int t = s - layer;
        if (t >= 0 && t < TSEQ) {
            const int p = s & 1;
            const bf16_t* src_lo = (layer == 0)
                ? (x_bf + (size_t)t * BATCH * HDIM)
                : (h_buf + (((size_t)(layer - 1) * 2 + (p ^ 1)) * BATCH * HDIM));
            const bf16_t* src_hi =
                h_buf + (((size_t)layer * 2 + (p ^ 1)) * BATCH * HDIM);

            const bf16_t* a_lo = src_lo + (size_t)arow * HDIM + quad * 8;
            const bf16_t* a_hi = src_hi + (size_t)arow * HDIM + quad * 8;

            floatx4 acc0 = {0.f, 0.f, 0.f, 0.f};
            floatx4 acc1 = {0.f, 0.f, 0.f, 0.f};

            #pragma unroll 4
            for (int kk = 0; kk < 16; ++kk) {
                bf16x8 a  = *(const bf16x8*)(a_lo + kk * 32);
                bf16x8 b0 = *(const bf16x8*)(b_base0 + kk * 32);
                bf16x8 b1 = *(const bf16x8*)(b_base1 + kk * 32);
                acc0 = mfma16(a, b0, acc0);
                acc1 = mfma16(a, b1, acc1);
            }
            #pragma unroll 4
            for (int kk = 0; kk < 16; ++kk) {
                bf16x8 a  = *(const bf16x8*)(a_hi + kk * 32);
                bf16x8 b0 = *(const bf16x8*)(b_base0 + 512 + kk * 32);
                bf16x8 b1 = *(const bf16x8*)(b_base1 + 512 + kk * 32);
                acc0 = mfma16(a, b0, acc0);
                acc1 = mfma16(a, b1, acc1);
            }

            // C/D layout: row = quad*4 + reg (batch), col = lane&15 (gate)
            #pragma unroll
            for (int r = 0; r < 4; ++r) {
                const int brow = m0 + quad * 4 + r;
                gates[brow * NROWS + nb0 + l15]      = acc0[r];
                gates[brow * NROWS + nb0 + 16 + l15] = acc1[r];
            }
            __syncthreads();

            // cell update: 64 batch x 16 units = 1024 items over 512 threads
            #pragma unroll
            for (int it = 0; it < 2; ++it) {
                const int id = tid + it * 512;
                const int b  = id >> 4;
                const int j  = id & 15;
                const float iv = gates[b * NROWS + j]      + bias[j];
                const float fv = gates[b * NROWS + 16 + j] + bias[16 + j];
                const float gv = gates[b * NROWS + 32 + j] + bias[32 + j];
                const float ov = gates[b * NROWS + 48 + j] + bias[48 + j];
                const float cold = cst[b * UNITS + j];
                const float cnew = sigm(fv) * cold + sigm(iv) * tanhf(gv);
                const float h    = sigm(ov) * tanhf(cnew);
                cst[b * UNITS + j] = cnew;
                h_buf[(((size_t)layer * 2 + p) * BATCH + b) * HDIM + u0 + j] =
                    (bf16_t)h;
                if (t == TSEQ - 1)
                    finals[((size_t)b * LAYERS + layer) * HDIM + u0 + j] = h;
            }
        }
        grid.sync();
    }
}

// FF head: per (b,l): 512 -> silu(128) -> 64, then interleave split + softplus.
__global__ void ff_epilogue(const float* __restrict__ finals,  // [B][L][H]
                            const float* __restrict__ ff1_w,   // [128][512]
                            const float* __restrict__ ff1_b,
                            const float* __restrict__ ff2_w,   // [64][128]
                            const float* __restrict__ ff2_b,
                            float* __restrict__ out)           // mean|scale
{
    __shared__ float fin[HDIM];
    __shared__ float hid[128];
    const int blk = blockIdx.x;        // b*8 + l
    const int b = blk >> 3, l = blk & 7;
    const int tid = threadIdx.x;       // 128

    const float* frow = finals + ((size_t)b * LAYERS + l) * HDIM;
    for (int k = tid; k < HDIM; k += 128) fin[k] = frow[k];
    __syncthreads();

    float acc = ff1_b[tid];
    const float* w1 = ff1_w + (size_t)tid * HDIM;
    #pragma unroll 4
    for (int k = 0; k < HDIM; ++k) acc = fmaf(fin[k], w1[k], acc);
    hid[tid] = acc * (1.0f / (1.0f + __expf(-acc)));   // silu
    __syncthreads();

    if (tid < 64) {
        float o = ff2_b[tid];
        const float* w2 = ff2_w + (size_t)tid * 128;
        #pragma unroll 4
        for (int k = 0; k < 128; ++k) o = fmaf(hid[k], w2[k], o);
        const int j = l * 64 + tid;        // column in (B, 512) flat h
        const int col = j >> 1;
        if ((j & 1) == 0) {
            out[b * 256 + col] = o;                        // mean
        } else {
            const float sp = fmaxf(o, 0.0f) + log1pf(__expf(-fabsf(o)));
            out[64 * 256 + b * 256 + col] = sp + 1e-8f;    // scale
        }
    }
}

extern "C" void kernel_launch(void* const* d_in, const int* in_sizes, int n_in,
                              void* d_out, int out_size, void* d_ws, size_t ws_size,
                              hipStream_t stream) {
    const float* x     = (const float*)d_in[0];
    const float* w_ih  = (const float*)d_in[1];
    const float* w_hh  = (const float*)d_in[2];
    const float* b_ih  = (const float*)d_in[3];
    const float* b_hh  = (const float*)d_in[4];
    const float* ff1_w = (const float*)d_in[5];
    const float* ff1_b = (const float*)d_in[6];
    const float* ff2_w = (const float*)d_in[7];
    const float* ff2_b = (const float*)d_in[8];
    float* out = (float*)d_out;

    char* ws = (char*)d_ws;
    bf16_t* x_bf   = (bf16_t*)ws;                                   // 16 MB
    bf16_t* h_buf  = (bf16_t*)(ws + (size_t)TSEQ * BATCH * HDIM * 2);  // 1 MB
    float*  finals = (float*)(ws + (size_t)TSEQ * BATCH * HDIM * 2
                                 + (size_t)LAYERS * 2 * BATCH * HDIM * 2); // 1 MB

    (void)in_sizes; (void)n_in; (void)out_size; (void)ws_size;

    hipFuncSetAttribute((const void*)lstm_main,
                        hipFuncAttributeMaxDynamicSharedMemorySize, LDS_TOTAL);

    void* args[] = {(void*)&x, (void*)&w_ih, (void*)&w_hh, (void*)&b_ih,
                    (void*)&b_hh, (void*)&x_bf, (void*)&h_buf, (void*)&finals};
    hipLaunchCooperativeKernel((const void*)lstm_main, dim3(256), dim3(512),
                               args, LDS_TOTAL, stream);

    ff_epilogue<<<dim3(512), dim3(128), 0, stream>>>(finals, ff1_w, ff1_b,
                                                     ff2_w, ff2_b, out);
}